// Round 1
// baseline (93.821 us; speedup 1.0000x reference)
//
#include <hip/hip_runtime.h>

#define S_LEN 4096
#define BATCH 2
#define DIM 64
#define RAD 128
#define NPOS 257
#define KEXT 4416              // 4096 + 5*64 (rel rows padded)
#define QREL_STR 260
#define PSTR 72                // P LDS row stride (x2B = 144B, 16B-aligned)

typedef short s16x8 __attribute__((ext_vector_type(8)));
typedef float f32x4 __attribute__((ext_vector_type(4)));
typedef unsigned short u16;
typedef unsigned int u32;

__device__ __forceinline__ u16 f2bf(float f) {
  union { float f; u32 u; } v; v.f = f;
  u32 u = v.u;
  return (u16)((u + 0x7FFFu + ((u >> 16) & 1u)) >> 16);  // RNE
}

// Kb_ext[b][t][d]: t<4096 -> bf16(K); 4096<=t<4353 -> bf16(rel[t-4096]); else 0
__global__ void prep_k(const float* __restrict__ K, const float* __restrict__ rel,
                       u16* __restrict__ Kb) {
  int b = blockIdx.y;
  int t = blockIdx.x * 4 + (threadIdx.x >> 6);
  int d = threadIdx.x & 63;
  float v = 0.f;
  if (t < S_LEN) v = K[((size_t)b * S_LEN + t) * DIM + d];
  else if (t - S_LEN < NPOS) v = rel[(size_t)(t - S_LEN) * DIM + d];
  Kb[((size_t)b * KEXT + t) * DIM + d] = f2bf(v);
}

// Vt[b][d][t] = bf16(V[b][t][d])  (LDS transpose, coalesced both sides)
__global__ void prep_v(const float* __restrict__ V, u16* __restrict__ Vt) {
  __shared__ float tile[64][65];
  int b = blockIdx.y;
  int t0 = blockIdx.x * 64;
  for (int i = threadIdx.x; i < 4096; i += 256) {
    int tl = i >> 6, d = i & 63;
    tile[tl][d] = V[((size_t)b * S_LEN + t0 + tl) * DIM + d];
  }
  __syncthreads();
  for (int i = threadIdx.x; i < 4096; i += 256) {
    int d = i >> 6, tl = i & 63;
    Vt[((size_t)b * DIM + d) * S_LEN + t0 + tl] = f2bf(tile[tl][d]);
  }
}

// Fused: energy = (QK^T + rel_shift)/8 written once; online softmax; Z = attn @ V.
// 8 waves: rg in {0,1} picks 16-row group, tq in {0..3} picks t-quarter.
__launch_bounds__(512, 1)
__global__ void attn_main(const float* __restrict__ Q,
                          const u16* __restrict__ Kb,
                          const u16* __restrict__ Vt,
                          float* __restrict__ energy,
                          float* __restrict__ Zout) {
  // union buffer: phase 1 = qrel[2][16][260] f32 (8320); phase 2 = Zbuf[8][16][64] (8192) + m(128) + l(128)
  __shared__ float uni[8448];
  __shared__ u16 plds[8 * 16 * PSTR];

  const int tid = threadIdx.x;
  const int lane = tid & 63;
  const int wid = tid >> 6;
  const int rg = wid >> 2, tq = wid & 3;
  const int l15 = lane & 15, q4 = lane >> 4;
  const int bx = blockIdx.x;
  const int b = bx >> 7;
  const int s0 = (bx & 127) * 32;
  const int rowbase = s0 + rg * 16;

  const u16* KbB = Kb + (size_t)b * KEXT * DIM;
  const u16* VtB = Vt + (size_t)b * DIM * S_LEN;

  // ---- Q A-fragments (rows rowbase..rowbase+15, bf16) ----
  s16x8 qfrag[2];
  {
    const float* qp = Q + ((size_t)b * S_LEN + rowbase + l15) * DIM + q4 * 8;
#pragma unroll
    for (int ks = 0; ks < 2; ++ks) {
      s16x8 f;
#pragma unroll
      for (int j = 0; j < 8; ++j) f[j] = (short)f2bf(qp[ks * 32 + j]);
      qfrag[ks] = f;
    }
  }

  const int koff_lane = l15 * DIM + q4 * 8;

  // ---- prologue: Q_rel via MFMA against appended rel rows ----
  for (int pt = tq; pt < 5; pt += 4) {
    f32x4 acc[4] = {};
    const u16* kp = KbB + (size_t)(S_LEN + pt * 64) * DIM + koff_lane;
#pragma unroll
    for (int ks = 0; ks < 2; ++ks)
#pragma unroll
      for (int nf = 0; nf < 4; ++nf) {
        s16x8 kf = *reinterpret_cast<const s16x8*>(kp + nf * 16 * DIM + ks * 32);
        acc[nf] = __builtin_amdgcn_mfma_f32_16x16x32_bf16(qfrag[ks], kf, acc[nf], 0, 0, 0);
      }
#pragma unroll
    for (int nf = 0; nf < 4; ++nf) {
      int p = pt * 64 + nf * 16 + l15;
      if (p < NPOS) {
#pragma unroll
        for (int reg = 0; reg < 4; ++reg)
          uni[(rg * 16 + q4 * 4 + reg) * QREL_STR + p] = acc[nf][reg];
      }
    }
  }
  __syncthreads();

  // ---- main loop over this wave's 16 t-tiles ----
  float mprev[4], lsum[4];
  f32x4 zacc[4] = {};
#pragma unroll
  for (int r = 0; r < 4; ++r) { mprev[r] = -INFINITY; lsum[r] = 0.f; }

  float* erow[4];
  int qbase[4];
#pragma unroll
  for (int reg = 0; reg < 4; ++reg) {
    int rloc = q4 * 4 + reg;
    erow[reg] = energy + ((size_t)b * S_LEN + s0 + rg * 16 + rloc) * S_LEN;
    qbase[reg] = (rg * 16 + rloc) * QREL_STR + RAD;
  }
  const int srow0 = s0 + rg * 16 + q4 * 4;
  u16* pw = plds + wid * 16 * PSTR;

  for (int it = 0; it < 16; ++it) {
    const int t0 = tq * 1024 + it * 64;

    f32x4 acc[4] = {};
    const u16* kp = KbB + (size_t)t0 * DIM + koff_lane;
    s16x8 kf[2][4];
#pragma unroll
    for (int ks = 0; ks < 2; ++ks)
#pragma unroll
      for (int nf = 0; nf < 4; ++nf)
        kf[ks][nf] = *reinterpret_cast<const s16x8*>(kp + nf * 16 * DIM + ks * 32);
#pragma unroll
    for (int ks = 0; ks < 2; ++ks)
#pragma unroll
      for (int nf = 0; nf < 4; ++nf)
        acc[nf] = __builtin_amdgcn_mfma_f32_16x16x32_bf16(qfrag[ks], kf[ks][nf], acc[nf], 0, 0, 0);

    // energy write + row stats
    float ev[4][4];
    float mt[4] = {-INFINITY, -INFINITY, -INFINITY, -INFINITY};
#pragma unroll
    for (int nf = 0; nf < 4; ++nf) {
      const int t = t0 + nf * 16 + l15;
#pragma unroll
      for (int reg = 0; reg < 4; ++reg) {
        int p = t - (srow0 + reg);
        p = (p < -RAD) ? -RAD : (p > RAD ? RAD : p);
        float e = (acc[nf][reg] + uni[qbase[reg] + p]) * 0.125f;
        erow[reg][t] = e;
        ev[nf][reg] = e;
        mt[reg] = fmaxf(mt[reg], e);
      }
    }

#pragma unroll
    for (int reg = 0; reg < 4; ++reg) {
      float m = mt[reg];
      m = fmaxf(m, __shfl_xor(m, 1));
      m = fmaxf(m, __shfl_xor(m, 2));
      m = fmaxf(m, __shfl_xor(m, 4));
      m = fmaxf(m, __shfl_xor(m, 8));
      const float mn = fmaxf(mprev[reg], m);
      const float alpha = __expf(mprev[reg] - mn);
      mprev[reg] = mn;
      lsum[reg] *= alpha;
#pragma unroll
      for (int dn = 0; dn < 4; ++dn) zacc[dn][reg] *= alpha;
      float rs = 0.f;
#pragma unroll
      for (int nf = 0; nf < 4; ++nf) {
        float pv = __expf(ev[nf][reg] - mn);
        rs += pv;
        pw[(q4 * 4 + reg) * PSTR + nf * 16 + l15] = f2bf(pv);
      }
      rs += __shfl_xor(rs, 1);
      rs += __shfl_xor(rs, 2);
      rs += __shfl_xor(rs, 4);
      rs += __shfl_xor(rs, 8);
      lsum[reg] += rs;
    }

    // PV MFMA (P from per-wave LDS, V from pre-transposed bf16 global)
    const u16* vp = VtB + (size_t)l15 * S_LEN + t0 + q4 * 8;
#pragma unroll
    for (int ks = 0; ks < 2; ++ks) {
      s16x8 pf = *reinterpret_cast<const s16x8*>(pw + l15 * PSTR + ks * 32 + q4 * 8);
#pragma unroll
      for (int dn = 0; dn < 4; ++dn) {
        s16x8 vf = *reinterpret_cast<const s16x8*>(vp + (size_t)dn * 16 * S_LEN + ks * 32);
        zacc[dn] = __builtin_amdgcn_mfma_f32_16x16x32_bf16(pf, vf, zacc[dn], 0, 0, 0);
      }
    }
  }

  // ---- cross-wave (t-quarter) combine; reuse uni as Zbuf/m/l ----
  __syncthreads();
#pragma unroll
  for (int dn = 0; dn < 4; ++dn)
#pragma unroll
    for (int reg = 0; reg < 4; ++reg)
      uni[((rg * 4 + tq) * 16 + q4 * 4 + reg) * 64 + dn * 16 + l15] = zacc[dn][reg];
  if (l15 == 0) {
#pragma unroll
    for (int reg = 0; reg < 4; ++reg) {
      uni[8192 + (rg * 4 + tq) * 16 + q4 * 4 + reg] = mprev[reg];
      uni[8320 + (rg * 4 + tq) * 16 + q4 * 4 + reg] = lsum[reg];
    }
  }
  __syncthreads();

#pragma unroll
  for (int rr = 0; rr < 4; ++rr) {
    const int row = tq * 4 + rr;
    float mf = -INFINITY;
#pragma unroll
    for (int w = 0; w < 4; ++w) mf = fmaxf(mf, uni[8192 + (rg * 4 + w) * 16 + row]);
    float lf = 0.f, z = 0.f;
#pragma unroll
    for (int w = 0; w < 4; ++w) {
      const float sc = __expf(uni[8192 + (rg * 4 + w) * 16 + row] - mf);
      lf += uni[8320 + (rg * 4 + w) * 16 + row] * sc;
      z  += uni[((rg * 4 + w) * 16 + row) * 64 + lane] * sc;
    }
    Zout[((size_t)b * S_LEN + s0 + rg * 16 + row) * DIM + lane] = z / lf;
  }
}

extern "C" void kernel_launch(void* const* d_in, const int* in_sizes, int n_in,
                              void* d_out, int out_size, void* d_ws, size_t ws_size,
                              hipStream_t stream) {
  const float* Q   = (const float*)d_in[0];
  const float* K   = (const float*)d_in[1];
  const float* V   = (const float*)d_in[2];
  const float* rel = (const float*)d_in[3];
  // d_in[4] = segment_ids (unused, segmented=False)

  u16* Kb = (u16*)d_ws;                                   // [B][KEXT][64] bf16
  u16* Vt = Kb + (size_t)BATCH * KEXT * DIM;              // [B][64][S] bf16

  float* energy = (float*)d_out;                          // [B][S][S]
  float* Zout   = energy + (size_t)BATCH * S_LEN * S_LEN; // [B][S][64]

  prep_k<<<dim3(KEXT / 4, BATCH), 256, 0, stream>>>(K, rel, Kb);
  prep_v<<<dim3(S_LEN / 64, BATCH), 256, 0, stream>>>(V, Vt);
  attn_main<<<dim3(BATCH * (S_LEN / 32)), 512, 0, stream>>>(Q, Kb, Vt, energy, Zout);
}

// Round 2
// 84.790 us; speedup vs baseline: 1.1065x; 1.1065x over previous
//
#include <hip/hip_runtime.h>

#define S_LEN 4096
#define BATCH 2
#define DIM 64
#define RAD 128
#define NPOS 257
#define KEXT 4416              // 4096 + 5*64 (rel rows padded)
#define QREL_STR 260
#define PSTR 72                // P LDS row stride in u16 (144B, 16B-aligned)

typedef short s16x8 __attribute__((ext_vector_type(8)));
typedef short s16x4 __attribute__((ext_vector_type(4)));
typedef float f32x4 __attribute__((ext_vector_type(4)));
typedef unsigned short u16;
typedef unsigned int u32;

__device__ __forceinline__ u16 f2bf(float f) {
  union { float f; u32 u; } v; v.f = f;
  u32 u = v.u;
  return (u16)((u + 0x7FFFu + ((u >> 16) & 1u)) >> 16);  // RNE
}

// Kb_ext[b][t][d]: t<4096 -> bf16(K); 4096<=t<4353 -> bf16(rel[t-4096]); else 0
__global__ void prep_k(const float* __restrict__ K, const float* __restrict__ rel,
                       u16* __restrict__ Kb) {
  int b = blockIdx.y;
  int t = blockIdx.x * 4 + (threadIdx.x >> 6);
  int d = threadIdx.x & 63;
  float v = 0.f;
  if (t < S_LEN) v = K[((size_t)b * S_LEN + t) * DIM + d];
  else if (t - S_LEN < NPOS) v = rel[(size_t)(t - S_LEN) * DIM + d];
  Kb[((size_t)b * KEXT + t) * DIM + d] = f2bf(v);
}

// Vt[b][d][t] = bf16(V[b][t][d])
__global__ void prep_v(const float* __restrict__ V, u16* __restrict__ Vt) {
  __shared__ float tile[64][65];
  int b = blockIdx.y;
  int t0 = blockIdx.x * 64;
  for (int i = threadIdx.x; i < 4096; i += 256) {
    int tl = i >> 6, d = i & 63;
    tile[tl][d] = V[((size_t)b * S_LEN + t0 + tl) * DIM + d];
  }
  __syncthreads();
  for (int i = threadIdx.x; i < 4096; i += 256) {
    int d = i >> 6, tl = i & 63;
    Vt[((size_t)b * DIM + d) * S_LEN + t0 + tl] = f2bf(tile[tl][d]);
  }
}

// 16 q-rows per block, 8 waves; wave w owns columns [w*512, (w+1)*512).
// Swapped-operand MFMAs keep q == l15 lane-local everywhere:
//   QK^T: mfma(kf, qf) -> D[t=q4*4+reg][q=l15]  -> energy float4 stores
//   PV:   mfma(vf, pf) -> D[d=q4*4+reg][q=l15]  -> alpha stays per-lane
__launch_bounds__(512, 4)
__global__ void attn_main(const float* __restrict__ Q,
                          const u16* __restrict__ Kb,
                          const u16* __restrict__ Vt,
                          float* __restrict__ energy,
                          float* __restrict__ Zout) {
  // phase 1: qrel[16][260] f32 (4160 f); phase 2: Zbuf[8][16][64] (8192 f) + m(128) + l(128)
  __shared__ float uni[8448];
  __shared__ u16 plds[8 * 16 * PSTR];

  const int tid = threadIdx.x;
  const int lane = tid & 63;
  const int wid = tid >> 6;
  const int l15 = lane & 15, q4 = lane >> 4;
  const int bx = blockIdx.x;
  const int b = bx >> 8;
  const int s0 = (bx & 255) * 16;

  const u16* KbB = Kb + (size_t)b * KEXT * DIM;
  const u16* VtB = Vt + (size_t)b * DIM * S_LEN;

  // ---- Q B-fragments (row s0+l15) ----
  s16x8 qfrag[2];
  {
    const float* qp = Q + ((size_t)b * S_LEN + s0 + l15) * DIM + q4 * 8;
#pragma unroll
    for (int ks = 0; ks < 2; ++ks) {
      f32x4 a = *reinterpret_cast<const f32x4*>(qp + ks * 32);
      f32x4 c = *reinterpret_cast<const f32x4*>(qp + ks * 32 + 4);
      s16x8 f;
#pragma unroll
      for (int j = 0; j < 4; ++j) { f[j] = (short)f2bf(a[j]); f[4 + j] = (short)f2bf(c[j]); }
      qfrag[ks] = f;
    }
  }

  const int koff_lane = l15 * DIM + q4 * 8;

  // ---- prologue: Q_rel[p][q] via mfma(rel, q) ----
  if (wid < 5) {
    f32x4 acc[4] = {};
    const u16* kp = KbB + (size_t)(S_LEN + wid * 64) * DIM + koff_lane;
#pragma unroll
    for (int ks = 0; ks < 2; ++ks)
#pragma unroll
      for (int nf = 0; nf < 4; ++nf) {
        s16x8 kf = *reinterpret_cast<const s16x8*>(kp + nf * 16 * DIM + ks * 32);
        acc[nf] = __builtin_amdgcn_mfma_f32_16x16x32_bf16(kf, qfrag[ks], acc[nf], 0, 0, 0);
      }
#pragma unroll
    for (int nf = 0; nf < 4; ++nf)
#pragma unroll
      for (int reg = 0; reg < 4; ++reg) {
        int p = wid * 64 + nf * 16 + q4 * 4 + reg;
        if (p < NPOS) uni[l15 * QREL_STR + p] = acc[nf][reg];
      }
  }
  __syncthreads();

  // ---- main loop: 8 t-tiles of 64 ----
  const int qglob = s0 + l15;
  float* erow = energy + ((size_t)b * S_LEN + qglob) * S_LEN;
  const int qoff = l15 * QREL_STR + RAD;
  u16* pw = plds + wid * 16 * PSTR;

  float mprev = -INFINITY, lsum = 0.f;
  f32x4 zacc[4] = {};

  for (int it = 0; it < 8; ++it) {
    const int t0 = wid * 512 + it * 64;

    f32x4 acc[4] = {};
    const u16* kp = KbB + (size_t)t0 * DIM + koff_lane;
#pragma unroll
    for (int ks = 0; ks < 2; ++ks)
#pragma unroll
      for (int nf = 0; nf < 4; ++nf) {
        s16x8 kf = *reinterpret_cast<const s16x8*>(kp + nf * 16 * DIM + ks * 32);
        acc[nf] = __builtin_amdgcn_mfma_f32_16x16x32_bf16(kf, qfrag[ks], acc[nf], 0, 0, 0);
      }

    // rel shift + scale, float4 energy store, lane-local max
    float mloc = -INFINITY;
#pragma unroll
    for (int nf = 0; nf < 4; ++nf) {
      const int tb = t0 + nf * 16 + q4 * 4;
#pragma unroll
      for (int reg = 0; reg < 4; ++reg) {
        int p = tb + reg - qglob;
        p = (p < -RAD) ? -RAD : (p > RAD ? RAD : p);
        float e = (acc[nf][reg] + uni[qoff + p]) * 0.125f;
        acc[nf][reg] = e;
        mloc = fmaxf(mloc, e);
      }
      *reinterpret_cast<f32x4*>(erow + tb) = acc[nf];
    }

    mloc = fmaxf(mloc, __shfl_xor(mloc, 16));
    mloc = fmaxf(mloc, __shfl_xor(mloc, 32));
    const float mn = fmaxf(mprev, mloc);
    const float alpha = __expf(mprev - mn);
    mprev = mn;
    lsum *= alpha;
#pragma unroll
    for (int dn = 0; dn < 4; ++dn) zacc[dn] *= alpha;

    float rs = 0.f;
#pragma unroll
    for (int nf = 0; nf < 4; ++nf) {
      s16x4 p4;
#pragma unroll
      for (int reg = 0; reg < 4; ++reg) {
        float pv = __expf(acc[nf][reg] - mn);
        rs += pv;
        p4[reg] = (short)f2bf(pv);
      }
      *reinterpret_cast<s16x4*>(pw + l15 * PSTR + nf * 16 + q4 * 4) = p4;
    }
    rs += __shfl_xor(rs, 16);
    rs += __shfl_xor(rs, 32);
    lsum += rs;

    // PV: mfma(vf, pf) -> zacc[dn] holds Z[d=dn*16+q4*4+reg][q=l15]
#pragma unroll
    for (int ks = 0; ks < 2; ++ks) {
      s16x8 pf = *reinterpret_cast<const s16x8*>(pw + l15 * PSTR + ks * 32 + q4 * 8);
#pragma unroll
      for (int dn = 0; dn < 4; ++dn) {
        s16x8 vf = *reinterpret_cast<const s16x8*>(
            VtB + (size_t)(dn * 16 + l15) * S_LEN + t0 + ks * 32 + q4 * 8);
        zacc[dn] = __builtin_amdgcn_mfma_f32_16x16x32_bf16(vf, pf, zacc[dn], 0, 0, 0);
      }
    }
  }

  // ---- cross-wave combine (8 column chunks) ----
  __syncthreads();
#pragma unroll
  for (int dn = 0; dn < 4; ++dn)
    *reinterpret_cast<f32x4*>(&uni[(wid * 16 + l15) * 64 + dn * 16 + q4 * 4]) = zacc[dn];
  if (q4 == 0) {
    uni[8192 + wid * 16 + l15] = mprev;
    uni[8320 + wid * 16 + l15] = lsum;
  }
  __syncthreads();

#pragma unroll
  for (int rr = 0; rr < 2; ++rr) {
    const int r = wid + rr * 8;
    float mf = -INFINITY;
#pragma unroll
    for (int w = 0; w < 8; ++w) mf = fmaxf(mf, uni[8192 + w * 16 + r]);
    float lf = 0.f, z = 0.f;
#pragma unroll
    for (int w = 0; w < 8; ++w) {
      const float sc = __expf(uni[8192 + w * 16 + r] - mf);
      lf += uni[8320 + w * 16 + r] * sc;
      z  += uni[(w * 16 + r) * 64 + lane] * sc;
    }
    Zout[((size_t)b * S_LEN + s0 + r) * DIM + lane] = z / lf;
  }
}

extern "C" void kernel_launch(void* const* d_in, const int* in_sizes, int n_in,
                              void* d_out, int out_size, void* d_ws, size_t ws_size,
                              hipStream_t stream) {
  const float* Q   = (const float*)d_in[0];
  const float* K   = (const float*)d_in[1];
  const float* V   = (const float*)d_in[2];
  const float* rel = (const float*)d_in[3];
  // d_in[4] = segment_ids (unused, segmented=False)

  u16* Kb = (u16*)d_ws;                                   // [B][KEXT][64] bf16
  u16* Vt = Kb + (size_t)BATCH * KEXT * DIM;              // [B][64][S] bf16

  float* energy = (float*)d_out;                          // [B][S][S]
  float* Zout   = energy + (size_t)BATCH * S_LEN * S_LEN; // [B][S][64]

  prep_k<<<dim3(KEXT / 4, BATCH), 256, 0, stream>>>(K, rel, Kb);
  prep_v<<<dim3(S_LEN / 64, BATCH), 256, 0, stream>>>(V, Vt);
  attn_main<<<dim3(BATCH * (S_LEN / 16)), 512, 0, stream>>>(Q, Kb, Vt, energy, Zout);
}

// Round 3
// 81.514 us; speedup vs baseline: 1.1510x; 1.0402x over previous
//
#include <hip/hip_runtime.h>

#define S_LEN 4096
#define BATCH 2
#define DIM 64
#define RAD 128
#define NPOS 257
#define KEXT 4416              // 4096 + 5*64 (rel rows padded)
#define QREL_STR 260
#define PSTR 72                // P LDS row stride in u16 (144B, 16B-aligned)
#define EPAD 68                // ebuf row stride in f32 (272B, breaks bank alias)

typedef short s16x8 __attribute__((ext_vector_type(8)));
typedef short s16x4 __attribute__((ext_vector_type(4)));
typedef float f32x4 __attribute__((ext_vector_type(4)));
typedef unsigned short u16;
typedef unsigned int u32;

__device__ __forceinline__ u16 f2bf(float f) {
  union { float f; u32 u; } v; v.f = f;
  u32 u = v.u;
  return (u16)((u + 0x7FFFu + ((u >> 16) & 1u)) >> 16);  // RNE
}

// Kb_ext[b][t][d]: t<4096 -> bf16(K); 4096<=t<4353 -> bf16(rel[t-4096]); else 0
__global__ void prep_k(const float* __restrict__ K, const float* __restrict__ rel,
                       u16* __restrict__ Kb) {
  int b = blockIdx.y;
  int t = blockIdx.x * 4 + (threadIdx.x >> 6);
  int d = threadIdx.x & 63;
  float v = 0.f;
  if (t < S_LEN) v = K[((size_t)b * S_LEN + t) * DIM + d];
  else if (t - S_LEN < NPOS) v = rel[(size_t)(t - S_LEN) * DIM + d];
  Kb[((size_t)b * KEXT + t) * DIM + d] = f2bf(v);
}

// Vt[b][d][t] = bf16(V[b][t][d])
__global__ void prep_v(const float* __restrict__ V, u16* __restrict__ Vt) {
  __shared__ float tile[64][65];
  int b = blockIdx.y;
  int t0 = blockIdx.x * 64;
  for (int i = threadIdx.x; i < 4096; i += 256) {
    int tl = i >> 6, d = i & 63;
    tile[tl][d] = V[((size_t)b * S_LEN + t0 + tl) * DIM + d];
  }
  __syncthreads();
  for (int i = threadIdx.x; i < 4096; i += 256) {
    int d = i >> 6, tl = i & 63;
    Vt[((size_t)b * DIM + d) * S_LEN + t0 + tl] = f2bf(tile[tl][d]);
  }
}

// 16 q-rows per block, 8 waves; wave w owns columns [w*512, (w+1)*512).
// Swapped-operand MFMAs keep q == l15 lane-local:
//   QK^T: mfma(kf, qf) -> D[t=q4*4+reg][q=l15]
//   PV:   mfma(vf, pf) -> D[d=q4*4+reg][q=l15]
// Energy stores go through a per-wave LDS tile so each store instruction is
// 4 rows x 256B contiguous (defeats the 16KB row-stride channel camping).
__launch_bounds__(512, 4)
__global__ void attn_main(const float* __restrict__ Q,
                          const u16* __restrict__ Kb,
                          const u16* __restrict__ Vt,
                          float* __restrict__ energy,
                          float* __restrict__ Zout) {
  __shared__ float qrel[16 * QREL_STR];   // 16640 B; rows: q (l15), cols: p
  __shared__ u16 plds[8 * 16 * PSTR];     // 18432 B
  __shared__ float ebuf[8 * 16 * EPAD];   // 34816 B; per-wave 16x68 energy tile
  // phase 2 reuse: ebuf[(w*16+r)*64+lane] = Zbuf; qrel[0..127]=m, qrel[128..255]=l

  const int tid = threadIdx.x;
  const int lane = tid & 63;
  const int wid = tid >> 6;
  const int l15 = lane & 15, q4 = lane >> 4;
  const int bx = blockIdx.x;
  const int b = bx >> 8;
  const int s0 = (bx & 255) * 16;

  const u16* KbB = Kb + (size_t)b * KEXT * DIM;
  const u16* VtB = Vt + (size_t)b * DIM * S_LEN;

  // ---- Q B-fragments (row s0+l15) ----
  s16x8 qfrag[2];
  {
    const float* qp = Q + ((size_t)b * S_LEN + s0 + l15) * DIM + q4 * 8;
#pragma unroll
    for (int ks = 0; ks < 2; ++ks) {
      f32x4 a = *reinterpret_cast<const f32x4*>(qp + ks * 32);
      f32x4 c = *reinterpret_cast<const f32x4*>(qp + ks * 32 + 4);
      s16x8 f;
#pragma unroll
      for (int j = 0; j < 4; ++j) { f[j] = (short)f2bf(a[j]); f[4 + j] = (short)f2bf(c[j]); }
      qfrag[ks] = f;
    }
  }

  const int koff_lane = l15 * DIM + q4 * 8;

  // ---- prologue: Q_rel[p][q] via mfma(rel, q) ----
  if (wid < 5) {
    f32x4 acc[4] = {};
    const u16* kp = KbB + (size_t)(S_LEN + wid * 64) * DIM + koff_lane;
#pragma unroll
    for (int ks = 0; ks < 2; ++ks)
#pragma unroll
      for (int nf = 0; nf < 4; ++nf) {
        s16x8 kf = *reinterpret_cast<const s16x8*>(kp + nf * 16 * DIM + ks * 32);
        acc[nf] = __builtin_amdgcn_mfma_f32_16x16x32_bf16(kf, qfrag[ks], acc[nf], 0, 0, 0);
      }
#pragma unroll
    for (int nf = 0; nf < 4; ++nf)
#pragma unroll
      for (int reg = 0; reg < 4; ++reg) {
        int p = wid * 64 + nf * 16 + q4 * 4 + reg;
        if (p < NPOS) qrel[l15 * QREL_STR + p] = acc[nf][reg];
      }
  }
  __syncthreads();

  // ---- main loop: 8 t-tiles of 64 ----
  const int qglob = s0 + l15;
  const int qoff = l15 * QREL_STR + RAD;
  u16* pw = plds + wid * 16 * PSTR;
  float* eb = ebuf + wid * 16 * EPAD;
  float* erow0 = energy + ((size_t)b * S_LEN + s0) * S_LEN;  // block row base

  float mprev = -INFINITY, lsum = 0.f;
  f32x4 zacc[4] = {};

  for (int it = 0; it < 8; ++it) {
    const int t0 = wid * 512 + it * 64;

    f32x4 acc[4] = {};
    const u16* kp = KbB + (size_t)t0 * DIM + koff_lane;
#pragma unroll
    for (int ks = 0; ks < 2; ++ks)
#pragma unroll
      for (int nf = 0; nf < 4; ++nf) {
        s16x8 kf = *reinterpret_cast<const s16x8*>(kp + nf * 16 * DIM + ks * 32);
        acc[nf] = __builtin_amdgcn_mfma_f32_16x16x32_bf16(kf, qfrag[ks], acc[nf], 0, 0, 0);
      }

    // rel shift + scale; stage into per-wave LDS tile; lane-local max
    float mloc = -INFINITY;
#pragma unroll
    for (int nf = 0; nf < 4; ++nf) {
      const int tb = t0 + nf * 16 + q4 * 4;
#pragma unroll
      for (int reg = 0; reg < 4; ++reg) {
        int p = tb + reg - qglob;
        p = (p < -RAD) ? -RAD : (p > RAD ? RAD : p);
        float e = (acc[nf][reg] + qrel[qoff + p]) * 0.125f;
        acc[nf][reg] = e;
        mloc = fmaxf(mloc, e);
      }
      *reinterpret_cast<f32x4*>(eb + l15 * EPAD + nf * 16 + q4 * 4) = acc[nf];
    }

    mloc = fmaxf(mloc, __shfl_xor(mloc, 16));
    mloc = fmaxf(mloc, __shfl_xor(mloc, 32));
    const float mn = fmaxf(mprev, mloc);
    const float alpha = __expf(mprev - mn);
    mprev = mn;
    lsum *= alpha;
#pragma unroll
    for (int dn = 0; dn < 4; ++dn) zacc[dn] *= alpha;

    float rs = 0.f;
#pragma unroll
    for (int nf = 0; nf < 4; ++nf) {
      s16x4 p4;
#pragma unroll
      for (int reg = 0; reg < 4; ++reg) {
        float pv = __expf(acc[nf][reg] - mn);
        rs += pv;
        p4[reg] = (short)f2bf(pv);
      }
      *reinterpret_cast<s16x4*>(pw + l15 * PSTR + nf * 16 + q4 * 4) = p4;
    }
    rs += __shfl_xor(rs, 16);
    rs += __shfl_xor(rs, 32);
    lsum += rs;

    // PV: mfma(vf, pf) -> zacc[dn] holds Z[d=dn*16+q4*4+reg][q=l15]
#pragma unroll
    for (int ks = 0; ks < 2; ++ks) {
      s16x8 pf = *reinterpret_cast<const s16x8*>(pw + l15 * PSTR + ks * 32 + q4 * 8);
#pragma unroll
      for (int dn = 0; dn < 4; ++dn) {
        s16x8 vf = *reinterpret_cast<const s16x8*>(
            VtB + (size_t)(dn * 16 + l15) * S_LEN + t0 + ks * 32 + q4 * 8);
        zacc[dn] = __builtin_amdgcn_mfma_f32_16x16x32_bf16(vf, pf, zacc[dn], 0, 0, 0);
      }
    }

    // energy store from LDS: per instr = 4 rows x 256B contiguous, nontemporal
#pragma unroll
    for (int c = 0; c < 4; ++c) {
      f32x4 v = *reinterpret_cast<const f32x4*>(eb + (c * 4 + q4) * EPAD + l15 * 4);
      __builtin_nontemporal_store(
          v, reinterpret_cast<f32x4*>(erow0 + (size_t)(c * 4 + q4) * S_LEN + t0 + l15 * 4));
    }
  }

  // ---- cross-wave combine (reuse ebuf as Zbuf, qrel[0..255] as m/l) ----
  __syncthreads();
#pragma unroll
  for (int dn = 0; dn < 4; ++dn)
    *reinterpret_cast<f32x4*>(&ebuf[(wid * 16 + l15) * 64 + dn * 16 + q4 * 4]) = zacc[dn];
  if (q4 == 0) {
    qrel[wid * 16 + l15] = mprev;
    qrel[128 + wid * 16 + l15] = lsum;
  }
  __syncthreads();

#pragma unroll
  for (int rr = 0; rr < 2; ++rr) {
    const int r = wid + rr * 8;
    float mf = -INFINITY;
#pragma unroll
    for (int w = 0; w < 8; ++w) mf = fmaxf(mf, qrel[w * 16 + r]);
    float lf = 0.f, z = 0.f;
#pragma unroll
    for (int w = 0; w < 8; ++w) {
      const float sc = __expf(qrel[w * 16 + r] - mf);
      lf += qrel[128 + w * 16 + r] * sc;
      z  += ebuf[(w * 16 + r) * 64 + lane] * sc;
    }
    Zout[((size_t)b * S_LEN + s0 + r) * DIM + lane] = z / lf;
  }
}

extern "C" void kernel_launch(void* const* d_in, const int* in_sizes, int n_in,
                              void* d_out, int out_size, void* d_ws, size_t ws_size,
                              hipStream_t stream) {
  const float* Q   = (const float*)d_in[0];
  const float* K   = (const float*)d_in[1];
  const float* V   = (const float*)d_in[2];
  const float* rel = (const float*)d_in[3];
  // d_in[4] = segment_ids (unused, segmented=False)

  u16* Kb = (u16*)d_ws;                                   // [B][KEXT][64] bf16
  u16* Vt = Kb + (size_t)BATCH * KEXT * DIM;              // [B][64][S] bf16

  float* energy = (float*)d_out;                          // [B][S][S]
  float* Zout   = energy + (size_t)BATCH * S_LEN * S_LEN; // [B][S][64]

  prep_k<<<dim3(KEXT / 4, BATCH), 256, 0, stream>>>(K, rel, Kb);
  prep_v<<<dim3(S_LEN / 64, BATCH), 256, 0, stream>>>(V, Vt);
  attn_main<<<dim3(BATCH * (S_LEN / 16)), 512, 0, stream>>>(Q, Kb, Vt, energy, Zout);
}